// Round 7
// baseline (178.156 us; speedup 1.0000x reference)
//
#include <hip/hip_runtime.h>
#include <stdint.h>

// ---------------- common types/helpers ----------------
typedef __attribute__((ext_vector_type(4))) float f32x4;
typedef _Float16 half8 __attribute__((ext_vector_type(8)));
typedef _Float16 half2v __attribute__((ext_vector_type(2)));

#define LDK 200  // LDS row pitch (halves): 192+8, rows 400B (16B-aligned)
#define QSCALE 0.17677669529663689f  // 32^-0.5

__device__ __forceinline__ float dot2f(unsigned int k2, unsigned int q2, float c) {
#if __has_builtin(__builtin_amdgcn_fdot2)
  return __builtin_amdgcn_fdot2(__builtin_bit_cast(half2v, k2),
                                __builtin_bit_cast(half2v, q2), c, false);
#else
  half2v a = __builtin_bit_cast(half2v, k2), b = __builtin_bit_cast(half2v, q2);
  return c + (float)a.x * (float)b.x + (float)a.y * (float)b.y;
#endif
}

#define MFMA16(A, B, C) __builtin_amdgcn_mfma_f32_16x16x32_f16(A, B, C, 0, 0, 0)

// ---------------- kernel 0: prep ----------------
// blocks [0,512): x NCHW f32 -> xh NHWC f16 (LDS-tiled transpose)
// blocks [512,659): qkv_w/proj_w -> f16 (q-scale folded), scaled qkv bias
__global__ __launch_bounds__(256) void prep(
    const float* __restrict__ x, const float* __restrict__ qw,
    const float* __restrict__ qb, const float* __restrict__ pw,
    _Float16* __restrict__ xh, _Float16* __restrict__ qwh,
    float* __restrict__ qbs, _Float16* __restrict__ pwh) {
  __shared__ _Float16 T[64 * LDK];
  const int bx = blockIdx.x, t = threadIdx.x;
  if (bx < 512) {
    const int bb = bx >> 6, hw0 = (bx & 63) << 6;
    const float* xb = x + (size_t)bb * 192 * 4096 + hw0;
    #pragma unroll
    for (int j = 0; j < 12; ++j) {
      int idx = j * 256 + t;
      int m4 = (idx & 15) * 4, c = idx >> 4;
      float4 v = *(const float4*)(xb + (size_t)c * 4096 + m4);
      T[(m4 + 0) * LDK + c] = (_Float16)v.x;
      T[(m4 + 1) * LDK + c] = (_Float16)v.y;
      T[(m4 + 2) * LDK + c] = (_Float16)v.z;
      T[(m4 + 3) * LDK + c] = (_Float16)v.w;
    }
    __syncthreads();
    _Float16* xo = xh + ((size_t)bb * 4096 + hw0) * 192;
    #pragma unroll
    for (int j = 0; j < 6; ++j) {
      int idx = j * 256 + t;
      int m = idx / 24, k8 = (idx % 24) * 8;
      *(uint4*)(xo + m * 192 + k8) = *(const uint4*)&T[m * LDK + k8];
    }
  } else {
    int i = (bx - 512) * 256 + t;
    if (i < 27648) {  // qkv_w
      float4 v = ((const float4*)qw)[i];
      int n = (i * 4) / 192;
      float sc = ((n % 192) < 64) ? QSCALE : 1.0f;
      _Float16* d = qwh + i * 4;
      d[0] = (_Float16)(v.x * sc); d[1] = (_Float16)(v.y * sc);
      d[2] = (_Float16)(v.z * sc); d[3] = (_Float16)(v.w * sc);
    } else if (i < 36864) {  // proj_w
      int k = i - 27648;
      float4 v = ((const float4*)pw)[k];
      _Float16* d = pwh + k * 4;
      d[0] = (_Float16)v.x; d[1] = (_Float16)v.y;
      d[2] = (_Float16)v.z; d[3] = (_Float16)v.w;
    } else if (i < 36864 + 576) {
      int n = i - 36864;
      qbs[n] = qb[n] * (((n % 192) < 64) ? QSCALE : 1.0f);
    }
  }
}

// ---------------- kernel 1: qkv GEMM ----------------
// Grid (128 px-groups, 9 n-tiles). B fragments live in registers (loaded once);
// 4 pixel-tiles per block with register-prefetched A staging. No global loads in K-loop.
// amdgpu_waves_per_eu(2,4): VGPR budget 256 (min-2-waves tier). r5/r6 lesson:
// default and __launch_bounds__(256,2) both left the allocator at the 64-VGPR /
// 8-waves tier, spilling ~80MB/launch of scratch traffic (WRITE 117MB vs 38MB out).
__global__ __launch_bounds__(256)
__attribute__((amdgpu_waves_per_eu(2, 4)))
void qkv_gemm(
    const _Float16* __restrict__ xh, const _Float16* __restrict__ wh,
    const float* __restrict__ qbs, _Float16* __restrict__ qkv) {
  __shared__ _Float16 Al[64 * LDK];
  const int t = threadIdx.x;
  const int n0 = blockIdx.y << 6;
  const int p0 = blockIdx.x << 8;  // 256 px per block (4 tiles of 64)
  const int lane = t & 63, wid = t >> 6;
  const int wm = (wid >> 1) * 32, wn = (wid & 1) * 32;
  const int lr = lane & 15, kb = (lane >> 4) * 8;
  const int r0 = (lane >> 4) * 4;

  // B fragments in regs: rows n0+wn+lr and +16, full K=192
  half8 B0[6], B1[6];
  #pragma unroll
  for (int k6 = 0; k6 < 6; ++k6) {
    B0[k6] = *(const half8*)(wh + (size_t)(n0 + wn + lr) * 192 + k6 * 32 + kb);
    B1[k6] = *(const half8*)(wh + (size_t)(n0 + wn + 16 + lr) * 192 + k6 * 32 + kb);
  }
  const float bs0 = qbs[n0 + wn + lr], bs1 = qbs[n0 + wn + 16 + lr];

  uint4 pf[6];
#define QSTAGE_LOAD(TT) { const _Float16* src = xh + ((size_t)p0 + (TT) * 64) * 192; \
  _Pragma("unroll") for (int q = 0; q < 6; ++q) pf[q] = *(const uint4*)(src + (q * 256 + t) * 8); }
#define QSTAGE_WRITE() { _Pragma("unroll") for (int q = 0; q < 6; ++q) { int id = q * 256 + t; \
  *(uint4*)&Al[(id / 24) * LDK + (id % 24) * 8] = pf[q]; } }

  QSTAGE_LOAD(0); QSTAGE_WRITE(); __syncthreads();

  for (int tt = 0; tt < 4; ++tt) {
    if (tt < 3) QSTAGE_LOAD(tt + 1);  // prefetch next tile (hides under MFMA)

    f32x4 acc[2][2];
    #pragma unroll
    for (int i = 0; i < 2; ++i)
      #pragma unroll
      for (int j = 0; j < 2; ++j)
        #pragma unroll
        for (int r = 0; r < 4; ++r) acc[i][j][r] = 0.0f;

    #pragma unroll
    for (int k6 = 0; k6 < 6; ++k6) {
      half8 a0 = *(const half8*)&Al[(wm + lr) * LDK + k6 * 32 + kb];
      half8 a1 = *(const half8*)&Al[(wm + 16 + lr) * LDK + k6 * 32 + kb];
      acc[0][0] = MFMA16(a0, B0[k6], acc[0][0]);
      acc[0][1] = MFMA16(a0, B1[k6], acc[0][1]);
      acc[1][0] = MFMA16(a1, B0[k6], acc[1][0]);
      acc[1][1] = MFMA16(a1, B1[k6], acc[1][1]);
    }

    // D: col (= weight n) = lane&15, row (= pixel) = (lane>>4)*4 + reg
    _Float16* opb = qkv + ((size_t)p0 + tt * 64) * 576 + n0;
    #pragma unroll
    for (int i = 0; i < 2; ++i)
      #pragma unroll
      for (int j = 0; j < 2; ++j) {
        int col = wn + j * 16 + lr;
        float bs = j ? bs1 : bs0;
        #pragma unroll
        for (int r = 0; r < 4; ++r)
          opb[(wm + i * 16 + r0 + r) * 576 + col] = (_Float16)(acc[i][j][r] + bs);
      }

    __syncthreads();
    if (tt < 3) { QSTAGE_WRITE(); __syncthreads(); }
  }
#undef QSTAGE_LOAD
#undef QSTAGE_WRITE
}

// ---------------- kernel 2: neighborhood attention (class-tiled, LDS halo) ----------------
template <int K, int DIL>
__device__ __forceinline__ void natten_branch(
    const _Float16* __restrict__ qkv, const float* __restrict__ rpb,
    _Float16* __restrict__ yo, const int branch, const int r,
    unsigned short* __restrict__ smem) {
  constexpr int RW = 2 * K - 1;
  constexpr int H8 = K + 7;        // halo span = 8 + K - 1
  constexpr int NH = H8 * H8;
  constexpr int NL = (K * K + 3) / 4;
  constexpr int LSTR = 40;         // halves per halo row (32 + 8 pad), 80B

  _Float16* Kl = (_Float16*)smem;
  _Float16* Vl = Kl + NH * LSTR;
  _Float16* Ql = Vl + NH * LSTR;
  float* rs = (float*)(Ql + 64 * LSTR);

  const int t = threadIdx.x;
  const int bh = r & 15;
  const int head = bh & 1, bb = bh >> 1;
  const int rr = r >> 4;
  int gh, gw, ti, tj, Lgh, Lgw;
  if (DIL == 1) {
    gh = 0; gw = 0; ti = (rr >> 3) * 8; tj = (rr & 7) * 8; Lgh = 64; Lgw = 64;
  } else if (DIL == 2) {
    int cls = rr >> 4, tile = rr & 15;
    gh = cls >> 1; gw = cls & 1; ti = (tile >> 2) * 8; tj = (tile & 3) * 8;
    Lgh = 32; Lgw = 32;
  } else {
    int cls = rr / 9, tile = rr % 9;
    gh = cls / 3; gw = cls % 3; ti = (tile / 3) * 8; tj = (tile % 3) * 8;
    Lgh = (64 - gh + 2) / 3; Lgw = (64 - gw + 2) / 3;
  }
  const int hoh = max(0, min(ti - K / 2, Lgh - K));
  const int how = max(0, min(tj - K / 2, Lgw - K));

  for (int i = t; i < RW * RW; i += 256) rs[i] = rpb[head * RW * RW + i];

  // stage halo K/V (each 16B chunk by one thread)
  const _Float16* kvb = qkv + (size_t)bb * 4096 * 576 + branch * 192 + 64 + head * 32;
  for (int L = t; L < NH * 8; L += 256) {
    int px = L >> 3, part = L & 7;
    int hr = px / H8, hc = px % H8;
    int cr = min(hoh + hr, Lgh - 1), cc = min(how + hc, Lgw - 1);
    int ph = gh + cr * DIL, pw2 = gw + cc * DIL;
    const _Float16* src = kvb + (size_t)(ph * 64 + pw2) * 576 + (part & 3) * 8 + ((part & 4) ? 64 : 0);
    _Float16* dst = ((part & 4) ? Vl : Kl) + px * LSTR + (part & 3) * 8;
    *(uint4*)dst = *(const uint4*)src;
  }
  // stage Q for 64 tile queries (clamped for ragged edges)
  {
    int qi = t >> 2, part = t & 3;
    int ci0 = min(ti + (qi >> 3), Lgh - 1), cj0 = min(tj + (qi & 7), Lgw - 1);
    int ph = gh + ci0 * DIL, pw2 = gw + cj0 * DIL;
    const _Float16* src = qkv + (size_t)((size_t)bb * 4096 + ph * 64 + pw2) * 576
                          + branch * 192 + head * 32 + part * 8;
    *(uint4*)(Ql + qi * LSTR + part * 8) = *(const uint4*)src;
  }
  __syncthreads();

  const int qi = t >> 2, sl = t & 3;
  const int ci = ti + (qi >> 3), cj = tj + (qi & 7);
  const bool valid = (ci < Lgh) && (cj < Lgw);

  int s0h = ci - K / 2; if (s0h < 0) s0h = 0; if (s0h > Lgh - K) s0h = Lgh - K;
  int s0w = cj - K / 2; if (s0w < 0) s0w = 0; if (s0w > Lgw - K) s0w = Lgw - K;
  const int rbase = s0h - hoh, cbase = s0w - how;          // in [0,7]
  const int bhb = s0h - ci + K - 1, bwb = s0w - cj + K - 1;

  // q packed pairs from LDS (broadcast within 4-lane group)
  unsigned int qh[16];
  #pragma unroll
  for (int u = 0; u < 4; ++u) {
    uint4 v = *(const uint4*)(Ql + qi * LSTR + u * 8);
    qh[u * 4 + 0] = v.x; qh[u * 4 + 1] = v.y; qh[u * 4 + 2] = v.z; qh[u * 4 + 3] = v.w;
  }

  // pass 1: scores for this lane's neighbors (n = sl + 4j)
  float s[NL];
  float mx = -1e30f;
  #pragma unroll
  for (int j = 0; j < NL; ++j) {
    int n = sl + 4 * j;
    if (n < K * K) {
      int kh = n / K, kw = n % K;
      int lidx = (rbase + kh) * H8 + (cbase + kw);
      const _Float16* kp = Kl + lidx * LSTR;
      float sc = rs[(bhb + kh) * RW + (bwb + kw)];
      #pragma unroll
      for (int u = 0; u < 4; ++u) {
        uint4 kv = *(const uint4*)(kp + u * 8);
        sc = dot2f(kv.x, qh[4 * u + 0], sc);
        sc = dot2f(kv.y, qh[4 * u + 1], sc);
        sc = dot2f(kv.z, qh[4 * u + 2], sc);
        sc = dot2f(kv.w, qh[4 * u + 3], sc);
      }
      s[j] = sc;
      mx = fmaxf(mx, sc);
    } else {
      s[j] = -1e30f;
    }
  }
  // merge max over the 4 lanes of this query
  mx = fmaxf(mx, __shfl_xor(mx, 1, 64));
  mx = fmaxf(mx, __shfl_xor(mx, 2, 64));

  float pw[NL];
  float l = 0.0f;
  #pragma unroll
  for (int j = 0; j < NL; ++j) { pw[j] = __expf(s[j] - mx); l += pw[j]; }
  l += __shfl_xor(l, 1, 64);
  l += __shfl_xor(l, 2, 64);

  // pass 2: PV with packed f16 accumulation
  half2v acch[16];
  #pragma unroll
  for (int i = 0; i < 16; ++i) acch[i] = (half2v)(_Float16)0.0f;
  #pragma unroll
  for (int j = 0; j < NL; ++j) {
    int n = sl + 4 * j;
    if (n < K * K) {
      int kh = n / K, kw = n % K;
      int lidx = (rbase + kh) * H8 + (cbase + kw);
      const _Float16* vp = Vl + lidx * LSTR;
      _Float16 ph = (_Float16)pw[j];
      half2v pp = {ph, ph};
      #pragma unroll
      for (int u = 0; u < 4; ++u) {
        uint4 vv = *(const uint4*)(vp + u * 8);
        acch[4 * u + 0] += pp * __builtin_bit_cast(half2v, vv.x);
        acch[4 * u + 1] += pp * __builtin_bit_cast(half2v, vv.y);
        acch[4 * u + 2] += pp * __builtin_bit_cast(half2v, vv.z);
        acch[4 * u + 3] += pp * __builtin_bit_cast(half2v, vv.w);
      }
    }
  }
  // butterfly-sum accumulators over the 4 lanes
  #pragma unroll
  for (int st = 1; st <= 2; st <<= 1) {
    #pragma unroll
    for (int i = 0; i < 16; ++i) {
      unsigned int o = __shfl_xor(__builtin_bit_cast(unsigned int, acch[i]), st, 64);
      acch[i] += __builtin_bit_cast(half2v, o);
    }
  }

  if (valid) {
    float inv = 1.0f / l;
    _Float16 ih = (_Float16)inv;
    half2v iv = {ih, ih};
    // lane sl writes dims [8sl, 8sl+8) = pair-regs acch[4sl .. 4sl+3]
    unsigned int a[16];
    #pragma unroll
    for (int i = 0; i < 16; ++i) a[i] = __builtin_bit_cast(unsigned int, acch[i]);
    uint4 pk;
    unsigned int r0, r1, r2, r3;
    r0 = (sl < 2) ? ((sl == 0) ? a[0] : a[4]) : ((sl == 2) ? a[8] : a[12]);
    r1 = (sl < 2) ? ((sl == 0) ? a[1] : a[5]) : ((sl == 2) ? a[9] : a[13]);
    r2 = (sl < 2) ? ((sl == 0) ? a[2] : a[6]) : ((sl == 2) ? a[10] : a[14]);
    r3 = (sl < 2) ? ((sl == 0) ? a[3] : a[7]) : ((sl == 2) ? a[11] : a[15]);
    pk.x = __builtin_bit_cast(unsigned int, __builtin_bit_cast(half2v, r0) * iv);
    pk.y = __builtin_bit_cast(unsigned int, __builtin_bit_cast(half2v, r1) * iv);
    pk.z = __builtin_bit_cast(unsigned int, __builtin_bit_cast(half2v, r2) * iv);
    pk.w = __builtin_bit_cast(unsigned int, __builtin_bit_cast(half2v, r3) * iv);
    const int p = bb * 4096 + (gh + ci * DIL) * 64 + (gw + cj * DIL);
    *(uint4*)(yo + (size_t)p * 192 + branch * 64 + head * 32 + sl * 8) = pk;
  }
}

__global__ __launch_bounds__(256) void natten_all(
    const _Float16* __restrict__ qkv,
    const float* __restrict__ rpb0, const float* __restrict__ rpb1,
    const float* __restrict__ rpb2, _Float16* __restrict__ yo) {
  __shared__ __align__(16) unsigned short smem[18624];  // max: K=7 -> 37.2 KB
  const int gid = blockIdx.x;
  if (gid < 1296)       natten_branch<7, 3>(qkv, rpb2, yo, 2, gid, smem);
  else if (gid < 2320)  natten_branch<5, 2>(qkv, rpb1, yo, 1, gid - 1296, smem);
  else                  natten_branch<3, 1>(qkv, rpb0, yo, 0, gid - 2320, smem);
}

// ---------------- kernel 3: proj GEMM (C^T for coalesced NCHW f32 stores) ----------------
// Grid (256 px-groups, 3 c-tiles). W fragments in registers; 2 pixel-tiles per block.
__global__ __launch_bounds__(256)
__attribute__((amdgpu_waves_per_eu(2, 4)))
void proj_gemm(
    const _Float16* __restrict__ y, const _Float16* __restrict__ wh,
    const float* __restrict__ bias, float* __restrict__ out) {
  __shared__ _Float16 Bl[64 * LDK];  // y tile (pixels x K)
  const int t = threadIdx.x;
  const int c0 = blockIdx.y << 6;
  const int p0 = blockIdx.x << 7;  // 128 px per block (2 tiles of 64)
  const int lane = t & 63, wid = t >> 6;
  const int wm = (wid >> 1) * 32, wn = (wid & 1) * 32;
  const int lr = lane & 15, kb = (lane >> 4) * 8;
  const int r0 = (lane >> 4) * 4;

  // W (A-operand) fragments in regs: rows c0+wm+lr and +16
  half8 A0[6], A1[6];
  #pragma unroll
  for (int k6 = 0; k6 < 6; ++k6) {
    A0[k6] = *(const half8*)(wh + (size_t)(c0 + wm + lr) * 192 + k6 * 32 + kb);
    A1[k6] = *(const half8*)(wh + (size_t)(c0 + wm + 16 + lr) * 192 + k6 * 32 + kb);
  }
  float bi[2][4];
  #pragma unroll
  for (int i = 0; i < 2; ++i)
    #pragma unroll
    for (int r = 0; r < 4; ++r) bi[i][r] = bias[c0 + wm + i * 16 + r0 + r];

  uint4 pf[6];
#define PSTAGE_LOAD(TT) { const _Float16* src = y + ((size_t)p0 + (TT) * 64) * 192; \
  _Pragma("unroll") for (int q = 0; q < 6; ++q) pf[q] = *(const uint4*)(src + (q * 256 + t) * 8); }
#define PSTAGE_WRITE() { _Pragma("unroll") for (int q = 0; q < 6; ++q) { int id = q * 256 + t; \
  *(uint4*)&Bl[(id / 24) * LDK + (id % 24) * 8] = pf[q]; } }

  PSTAGE_LOAD(0); PSTAGE_WRITE(); __syncthreads();

  for (int tt = 0; tt < 2; ++tt) {
    if (tt < 1) PSTAGE_LOAD(tt + 1);

    f32x4 acc[2][2];
    #pragma unroll
    for (int i = 0; i < 2; ++i)
      #pragma unroll
      for (int j = 0; j < 2; ++j)
        #pragma unroll
        for (int r = 0; r < 4; ++r) acc[i][j][r] = 0.0f;

    #pragma unroll
    for (int k6 = 0; k6 < 6; ++k6) {
      half8 b0 = *(const half8*)&Bl[(wn + lr) * LDK + k6 * 32 + kb];
      half8 b1 = *(const half8*)&Bl[(wn + 16 + lr) * LDK + k6 * 32 + kb];
      acc[0][0] = MFMA16(A0[k6], b0, acc[0][0]);
      acc[0][1] = MFMA16(A0[k6], b1, acc[0][1]);
      acc[1][0] = MFMA16(A1[k6], b0, acc[1][0]);
      acc[1][1] = MFMA16(A1[k6], b1, acc[1][1]);
    }

    const int gp = p0 + tt * 64;
    const int bb = gp >> 12, hw0 = gp & 4095;
    float* op = out + (size_t)bb * 192 * 4096 + hw0;
    #pragma unroll
    for (int i = 0; i < 2; ++i)
      #pragma unroll
      for (int j = 0; j < 2; ++j) {
        int m = wn + j * 16 + lr;  // pixel (D col)
        #pragma unroll
        for (int r = 0; r < 4; ++r) {
          int c = c0 + wm + i * 16 + r0 + r;  // out channel (D row)
          op[(size_t)c * 4096 + m] = acc[i][j][r] + bi[i][r];
        }
      }

    __syncthreads();
    if (tt < 1) { PSTAGE_WRITE(); __syncthreads(); }
  }
#undef PSTAGE_LOAD
#undef PSTAGE_WRITE
}

// ---------------- launch ----------------
extern "C" void kernel_launch(void* const* d_in, const int* in_sizes, int n_in,
                              void* d_out, int out_size, void* d_ws, size_t ws_size,
                              hipStream_t stream) {
  const float* x      = (const float*)d_in[0];
  const float* qkv_w  = (const float*)d_in[1];
  const float* qkv_b  = (const float*)d_in[2];
  const float* proj_w = (const float*)d_in[3];
  const float* proj_b = (const float*)d_in[4];
  const float* rpb0   = (const float*)d_in[5];
  const float* rpb1   = (const float*)d_in[6];
  const float* rpb2   = (const float*)d_in[7];

  // ws layout (~63 MB of ~256 MB): qkv f16, yb f16, xh f16, qwh f16, pwh f16, qbs f32
  _Float16* qkv = (_Float16*)d_ws;                    // 32768*576
  _Float16* yb  = qkv + (size_t)32768 * 576;          // 32768*192
  _Float16* xh  = yb + (size_t)32768 * 192;           // 32768*192
  _Float16* qwh = xh + (size_t)32768 * 192;           // 110592
  _Float16* pwh = qwh + 110592;                       // 36864
  float*    qbs = (float*)(pwh + 36864);              // 576
  float* out = (float*)d_out;

  prep<<<dim3(659), 256, 0, stream>>>(x, qkv_w, qkv_b, proj_w, xh, qwh, qbs, pwh);
  qkv_gemm<<<dim3(128, 9), 256, 0, stream>>>(xh, qwh, qbs, qkv);
  natten_all<<<dim3(3344), 256, 0, stream>>>(qkv, rpb0, rpb1, rpb2, yb);
  proj_gemm<<<dim3(256, 3), 256, 0, stream>>>(yb, pwh, proj_b, out);
}

// Round 8
// 140.338 us; speedup vs baseline: 1.2695x; 1.2695x over previous
//
#include <hip/hip_runtime.h>
#include <stdint.h>

// ---------------- common types/helpers ----------------
typedef __attribute__((ext_vector_type(4))) float f32x4;
typedef _Float16 half8 __attribute__((ext_vector_type(8)));
typedef _Float16 half2v __attribute__((ext_vector_type(2)));

#define LDK 200  // padded LDS row pitch (halves): 192+8, rows 400B (16B-aligned)
#define QSCALE 0.17677669529663689f  // 32^-0.5

__device__ __forceinline__ float dot2f(unsigned int k2, unsigned int q2, float c) {
#if __has_builtin(__builtin_amdgcn_fdot2)
  return __builtin_amdgcn_fdot2(__builtin_bit_cast(half2v, k2),
                                __builtin_bit_cast(half2v, q2), c, false);
#else
  half2v a = __builtin_bit_cast(half2v, k2), b = __builtin_bit_cast(half2v, q2);
  return c + (float)a.x * (float)b.x + (float)a.y * (float)b.y;
#endif
}

#define MFMA16(A, B, C) __builtin_amdgcn_mfma_f32_16x16x32_f16(A, B, C, 0, 0, 0)

// async global->LDS, 16B per lane; LDS dest = uniform base + lane*16
#define GLDS16(gsrc, ldst)                                                      \
  __builtin_amdgcn_global_load_lds(                                             \
      (const __attribute__((address_space(1))) void*)(gsrc),                    \
      (__attribute__((address_space(3))) void*)(ldst), 16, 0, 0)

// ---------------- kernel 0: prep ----------------
// blocks [0,512): x NCHW f32 -> xh NHWC f16 (LDS-tiled transpose)
// blocks [512,587): weights -> f16 in XOR-swizzled chunk layout
//   W_sw[row*192 + ((chunk ^ (row&7))*8)] = W[row][chunk*8 ..]   (chunk = 16B of 8 halves)
//   so a LINEAR global_load_lds image of a 64-row tile is bank-conflict-free
//   under the matching ds_read XOR. qkv bias scaled by QSCALE for q-channels.
__global__ __launch_bounds__(256) void prep(
    const float* __restrict__ x, const float* __restrict__ qw,
    const float* __restrict__ qb, const float* __restrict__ pw,
    _Float16* __restrict__ xh, _Float16* __restrict__ qwh,
    float* __restrict__ qbs, _Float16* __restrict__ pwh) {
  __shared__ __align__(16) _Float16 T[64 * LDK];
  const int bx = blockIdx.x, t = threadIdx.x;
  if (bx < 512) {
    const int bb = bx >> 6, hw0 = (bx & 63) << 6;
    const float* xb = x + (size_t)bb * 192 * 4096 + hw0;
    #pragma unroll
    for (int j = 0; j < 12; ++j) {
      int idx = j * 256 + t;
      int m4 = (idx & 15) * 4, c = idx >> 4;
      float4 v = *(const float4*)(xb + (size_t)c * 4096 + m4);
      T[(m4 + 0) * LDK + c] = (_Float16)v.x;
      T[(m4 + 1) * LDK + c] = (_Float16)v.y;
      T[(m4 + 2) * LDK + c] = (_Float16)v.z;
      T[(m4 + 3) * LDK + c] = (_Float16)v.w;
    }
    __syncthreads();
    _Float16* xo = xh + ((size_t)bb * 4096 + hw0) * 192;
    #pragma unroll
    for (int j = 0; j < 6; ++j) {
      int idx = j * 256 + t;
      int m = idx / 24, k8 = (idx % 24) * 8;
      *(uint4*)(xo + m * 192 + k8) = *(const uint4*)&T[m * LDK + k8];
    }
  } else {
    int i = (bx - 512) * 256 + t;  // chunk id
    if (i < 13824) {               // qkv_w: 576 rows x 24 chunks
      int n = i / 24, c = i % 24;
      const float* s = qw + n * 192 + c * 8;
      float sc = ((n % 192) < 64) ? QSCALE : 1.0f;
      half8 h = {(_Float16)(s[0] * sc), (_Float16)(s[1] * sc),
                 (_Float16)(s[2] * sc), (_Float16)(s[3] * sc),
                 (_Float16)(s[4] * sc), (_Float16)(s[5] * sc),
                 (_Float16)(s[6] * sc), (_Float16)(s[7] * sc)};
      *(half8*)(qwh + n * 192 + ((c ^ (n & 7)) << 3)) = h;
    } else if (i < 18432) {        // proj_w: 192 rows x 24 chunks
      int k = i - 13824;
      int n = k / 24, c = k % 24;
      const float* s = pw + n * 192 + c * 8;
      half8 h = {(_Float16)s[0], (_Float16)s[1], (_Float16)s[2], (_Float16)s[3],
                 (_Float16)s[4], (_Float16)s[5], (_Float16)s[6], (_Float16)s[7]};
      *(half8*)(pwh + n * 192 + ((c ^ (n & 7)) << 3)) = h;
    } else if (i < 19008) {
      int n = i - 18432;
      qbs[n] = qb[n] * (((n % 192) < 64) ? QSCALE : 1.0f);
    }
  }
}

// ---------------- kernel 1: qkv GEMM ----------------
// Grid 512: one 64-px tile per block, A staged once (padded LDS);
// n-loop over 9 W-tiles with DOUBLE-BUFFERED global_load_lds (zero data VGPRs,
// async across iterations; __syncthreads' implicit vmcnt(0) drains).
// Steady-state live VGPRs ~50 -> fits the 64-VGPR tier, no spill (r5-r7 lesson).
__global__ __launch_bounds__(256) void qkv_gemm(
    const _Float16* __restrict__ xh, const _Float16* __restrict__ wh,
    const float* __restrict__ qbs, _Float16* __restrict__ qkv) {
  __shared__ __align__(16) _Float16 Al[64 * LDK];
  __shared__ __align__(16) _Float16 Bsw[2][64 * 192];
  const int t = threadIdx.x;
  const int tm = blockIdx.x;  // 512 pixel tiles
  const int lane = t & 63, wid = t >> 6;
  const int wm = (wid >> 1) * 32, wn = (wid & 1) * 32;
  const int lr = lane & 15, hi = lane >> 4;
  const int kb = hi * 8, r0 = hi * 4;
  const int xr = lr & 7;  // row-XOR for swizzled W reads

  // async: W tile 0 -> LDS (1536 chunks; 6 instr/wave)
  #pragma unroll
  for (int i = 0; i < 6; ++i)
    GLDS16(wh + (wid * 6 + i) * 512 + lane * 8, &Bsw[0][(wid * 6 + i) * 512]);

  // A tile: reg-staged into padded LDS (transient regs only)
  {
    const _Float16* asrc = xh + (size_t)(tm * 64) * 192;
    uint4 av[6];
    #pragma unroll
    for (int q = 0; q < 6; ++q) av[q] = *(const uint4*)(asrc + (q * 256 + t) * 8);
    #pragma unroll
    for (int q = 0; q < 6; ++q) {
      int id = q * 256 + t;
      *(uint4*)&Al[(id / 24) * LDK + (id % 24) * 8] = av[q];
    }
  }
  __syncthreads();  // drains A loads + W0 gload_lds

  _Float16* opb = qkv + (size_t)(tm * 64) * 576;
  for (int it = 0; it < 9; ++it) {
    if (it < 8) {  // prefetch next W tile into the other buffer
      const _Float16* wsrc = wh + (it + 1) * 12288;
      _Float16* bdst = &Bsw[(it + 1) & 1][0];
      #pragma unroll
      for (int i = 0; i < 6; ++i)
        GLDS16(wsrc + (wid * 6 + i) * 512 + lane * 8, bdst + (wid * 6 + i) * 512);
    }
    const _Float16* bc = &Bsw[it & 1][0];

    f32x4 acc[2][2];
    #pragma unroll
    for (int i2 = 0; i2 < 2; ++i2)
      #pragma unroll
      for (int j = 0; j < 2; ++j)
        #pragma unroll
        for (int r = 0; r < 4; ++r) acc[i2][j][r] = 0.0f;

    #pragma unroll
    for (int k6 = 0; k6 < 6; ++k6) {
      half8 a0 = *(const half8*)&Al[(wm + lr) * LDK + k6 * 32 + kb];
      half8 a1 = *(const half8*)&Al[(wm + 16 + lr) * LDK + k6 * 32 + kb];
      const int cs = ((k6 * 4 + hi) ^ xr) << 3;  // swizzled chunk offset (halves)
      half8 b0 = *(const half8*)&bc[(wn + lr) * 192 + cs];
      half8 b1 = *(const half8*)&bc[(wn + 16 + lr) * 192 + cs];
      acc[0][0] = MFMA16(a0, b0, acc[0][0]);
      acc[0][1] = MFMA16(a0, b1, acc[0][1]);
      acc[1][0] = MFMA16(a1, b0, acc[1][0]);
      acc[1][1] = MFMA16(a1, b1, acc[1][1]);
    }

    // D: col (= weight n) = lane&15, row (= pixel) = hi*4 + reg
    const int n0 = it * 64;
    const float bs0 = qbs[n0 + wn + lr], bs1 = qbs[n0 + wn + 16 + lr];
    #pragma unroll
    for (int i2 = 0; i2 < 2; ++i2)
      #pragma unroll
      for (int j = 0; j < 2; ++j) {
        int col = n0 + wn + j * 16 + lr;
        float bs = j ? bs1 : bs0;
        #pragma unroll
        for (int r = 0; r < 4; ++r)
          opb[(wm + i2 * 16 + r0 + r) * 576 + col] = (_Float16)(acc[i2][j][r] + bs);
      }
    __syncthreads();  // implicit vmcnt(0): next W tile arrived; all reads of bc done
  }
}

// ---------------- kernel 2: neighborhood attention (class-tiled, LDS halo) ----------------
template <int K, int DIL>
__device__ __forceinline__ void natten_branch(
    const _Float16* __restrict__ qkv, const float* __restrict__ rpb,
    _Float16* __restrict__ yo, const int branch, const int r,
    unsigned short* __restrict__ smem) {
  constexpr int RW = 2 * K - 1;
  constexpr int H8 = K + 7;        // halo span = 8 + K - 1
  constexpr int NH = H8 * H8;
  constexpr int NL = (K * K + 3) / 4;
  constexpr int LSTR = 40;         // halves per halo row (32 + 8 pad), 80B

  _Float16* Kl = (_Float16*)smem;
  _Float16* Vl = Kl + NH * LSTR;
  _Float16* Ql = Vl + NH * LSTR;
  float* rs = (float*)(Ql + 64 * LSTR);

  const int t = threadIdx.x;
  const int bh = r & 15;
  const int head = bh & 1, bb = bh >> 1;
  const int rr = r >> 4;
  int gh, gw, ti, tj, Lgh, Lgw;
  if (DIL == 1) {
    gh = 0; gw = 0; ti = (rr >> 3) * 8; tj = (rr & 7) * 8; Lgh = 64; Lgw = 64;
  } else if (DIL == 2) {
    int cls = rr >> 4, tile = rr & 15;
    gh = cls >> 1; gw = cls & 1; ti = (tile >> 2) * 8; tj = (tile & 3) * 8;
    Lgh = 32; Lgw = 32;
  } else {
    int cls = rr / 9, tile = rr % 9;
    gh = cls / 3; gw = cls % 3; ti = (tile / 3) * 8; tj = (tile % 3) * 8;
    Lgh = (64 - gh + 2) / 3; Lgw = (64 - gw + 2) / 3;
  }
  const int hoh = max(0, min(ti - K / 2, Lgh - K));
  const int how = max(0, min(tj - K / 2, Lgw - K));

  for (int i = t; i < RW * RW; i += 256) rs[i] = rpb[head * RW * RW + i];

  // stage halo K/V (each 16B chunk by one thread)
  const _Float16* kvb = qkv + (size_t)bb * 4096 * 576 + branch * 192 + 64 + head * 32;
  for (int L = t; L < NH * 8; L += 256) {
    int px = L >> 3, part = L & 7;
    int hr = px / H8, hc = px % H8;
    int cr = min(hoh + hr, Lgh - 1), cc = min(how + hc, Lgw - 1);
    int ph = gh + cr * DIL, pw2 = gw + cc * DIL;
    const _Float16* src = kvb + (size_t)(ph * 64 + pw2) * 576 + (part & 3) * 8 + ((part & 4) ? 64 : 0);
    _Float16* dst = ((part & 4) ? Vl : Kl) + px * LSTR + (part & 3) * 8;
    *(uint4*)dst = *(const uint4*)src;
  }
  // stage Q for 64 tile queries (clamped for ragged edges)
  {
    int qi = t >> 2, part = t & 3;
    int ci0 = min(ti + (qi >> 3), Lgh - 1), cj0 = min(tj + (qi & 7), Lgw - 1);
    int ph = gh + ci0 * DIL, pw2 = gw + cj0 * DIL;
    const _Float16* src = qkv + (size_t)((size_t)bb * 4096 + ph * 64 + pw2) * 576
                          + branch * 192 + head * 32 + part * 8;
    *(uint4*)(Ql + qi * LSTR + part * 8) = *(const uint4*)src;
  }
  __syncthreads();

  const int qi = t >> 2, sl = t & 3;
  const int ci = ti + (qi >> 3), cj = tj + (qi & 7);
  const bool valid = (ci < Lgh) && (cj < Lgw);

  int s0h = ci - K / 2; if (s0h < 0) s0h = 0; if (s0h > Lgh - K) s0h = Lgh - K;
  int s0w = cj - K / 2; if (s0w < 0) s0w = 0; if (s0w > Lgw - K) s0w = Lgw - K;
  const int rbase = s0h - hoh, cbase = s0w - how;          // in [0,7]
  const int bhb = s0h - ci + K - 1, bwb = s0w - cj + K - 1;

  // q packed pairs from LDS (broadcast within 4-lane group)
  unsigned int qh[16];
  #pragma unroll
  for (int u = 0; u < 4; ++u) {
    uint4 v = *(const uint4*)(Ql + qi * LSTR + u * 8);
    qh[u * 4 + 0] = v.x; qh[u * 4 + 1] = v.y; qh[u * 4 + 2] = v.z; qh[u * 4 + 3] = v.w;
  }

  // pass 1: scores for this lane's neighbors (n = sl + 4j)
  float s[NL];
  float mx = -1e30f;
  #pragma unroll
  for (int j = 0; j < NL; ++j) {
    int n = sl + 4 * j;
    if (n < K * K) {
      int kh = n / K, kw = n % K;
      int lidx = (rbase + kh) * H8 + (cbase + kw);
      const _Float16* kp = Kl + lidx * LSTR;
      float sc = rs[(bhb + kh) * RW + (bwb + kw)];
      #pragma unroll
      for (int u = 0; u < 4; ++u) {
        uint4 kv = *(const uint4*)(kp + u * 8);
        sc = dot2f(kv.x, qh[4 * u + 0], sc);
        sc = dot2f(kv.y, qh[4 * u + 1], sc);
        sc = dot2f(kv.z, qh[4 * u + 2], sc);
        sc = dot2f(kv.w, qh[4 * u + 3], sc);
      }
      s[j] = sc;
      mx = fmaxf(mx, sc);
    } else {
      s[j] = -1e30f;
    }
  }
  // merge max over the 4 lanes of this query
  mx = fmaxf(mx, __shfl_xor(mx, 1, 64));
  mx = fmaxf(mx, __shfl_xor(mx, 2, 64));

  float pw[NL];
  float l = 0.0f;
  #pragma unroll
  for (int j = 0; j < NL; ++j) { pw[j] = __expf(s[j] - mx); l += pw[j]; }
  l += __shfl_xor(l, 1, 64);
  l += __shfl_xor(l, 2, 64);

  // pass 2: PV with packed f16 accumulation
  half2v acch[16];
  #pragma unroll
  for (int i = 0; i < 16; ++i) acch[i] = (half2v)(_Float16)0.0f;
  #pragma unroll
  for (int j = 0; j < NL; ++j) {
    int n = sl + 4 * j;
    if (n < K * K) {
      int kh = n / K, kw = n % K;
      int lidx = (rbase + kh) * H8 + (cbase + kw);
      const _Float16* vp = Vl + lidx * LSTR;
      _Float16 ph = (_Float16)pw[j];
      half2v pp = {ph, ph};
      #pragma unroll
      for (int u = 0; u < 4; ++u) {
        uint4 vv = *(const uint4*)(vp + u * 8);
        acch[4 * u + 0] += pp * __builtin_bit_cast(half2v, vv.x);
        acch[4 * u + 1] += pp * __builtin_bit_cast(half2v, vv.y);
        acch[4 * u + 2] += pp * __builtin_bit_cast(half2v, vv.z);
        acch[4 * u + 3] += pp * __builtin_bit_cast(half2v, vv.w);
      }
    }
  }
  // butterfly-sum accumulators over the 4 lanes
  #pragma unroll
  for (int st = 1; st <= 2; st <<= 1) {
    #pragma unroll
    for (int i = 0; i < 16; ++i) {
      unsigned int o = __shfl_xor(__builtin_bit_cast(unsigned int, acch[i]), st, 64);
      acch[i] += __builtin_bit_cast(half2v, o);
    }
  }

  if (valid) {
    float inv = 1.0f / l;
    _Float16 ih = (_Float16)inv;
    half2v iv = {ih, ih};
    // lane sl writes dims [8sl, 8sl+8) = pair-regs acch[4sl .. 4sl+3]
    unsigned int a[16];
    #pragma unroll
    for (int i = 0; i < 16; ++i) a[i] = __builtin_bit_cast(unsigned int, acch[i]);
    uint4 pk;
    unsigned int r0, r1, r2, r3;
    r0 = (sl < 2) ? ((sl == 0) ? a[0] : a[4]) : ((sl == 2) ? a[8] : a[12]);
    r1 = (sl < 2) ? ((sl == 0) ? a[1] : a[5]) : ((sl == 2) ? a[9] : a[13]);
    r2 = (sl < 2) ? ((sl == 0) ? a[2] : a[6]) : ((sl == 2) ? a[10] : a[14]);
    r3 = (sl < 2) ? ((sl == 0) ? a[3] : a[7]) : ((sl == 2) ? a[11] : a[15]);
    pk.x = __builtin_bit_cast(unsigned int, __builtin_bit_cast(half2v, r0) * iv);
    pk.y = __builtin_bit_cast(unsigned int, __builtin_bit_cast(half2v, r1) * iv);
    pk.z = __builtin_bit_cast(unsigned int, __builtin_bit_cast(half2v, r2) * iv);
    pk.w = __builtin_bit_cast(unsigned int, __builtin_bit_cast(half2v, r3) * iv);
    const int p = bb * 4096 + (gh + ci * DIL) * 64 + (gw + cj * DIL);
    *(uint4*)(yo + (size_t)p * 192 + branch * 64 + head * 32 + sl * 8) = pk;
  }
}

__global__ __launch_bounds__(256) void natten_all(
    const _Float16* __restrict__ qkv,
    const float* __restrict__ rpb0, const float* __restrict__ rpb1,
    const float* __restrict__ rpb2, _Float16* __restrict__ yo) {
  __shared__ __align__(16) unsigned short smem[18624];  // max: K=7 -> 37.2 KB
  const int gid = blockIdx.x;
  if (gid < 1296)       natten_branch<7, 3>(qkv, rpb2, yo, 2, gid, smem);
  else if (gid < 2320)  natten_branch<5, 2>(qkv, rpb1, yo, 1, gid - 1296, smem);
  else                  natten_branch<3, 1>(qkv, rpb0, yo, 0, gid - 2320, smem);
}

// ---------------- kernel 3: proj GEMM (C^T for coalesced NCHW f32 stores) ----------------
// Grid (512 px-tiles, 3 c-tiles). W tile via swizzled global_load_lds (L2-hot);
// y tile reg-staged into padded LDS. Single compute phase; ~50 live VGPRs.
__global__ __launch_bounds__(256) void proj_gemm(
    const _Float16* __restrict__ y, const _Float16* __restrict__ wh,
    const float* __restrict__ bias, float* __restrict__ out) {
  __shared__ __align__(16) _Float16 Bl[64 * LDK];   // y (pixels x K), padded
  __shared__ __align__(16) _Float16 Wsw[64 * 192];  // W tile, swizzled-linear
  const int t = threadIdx.x;
  const int tp = blockIdx.x, c0 = blockIdx.y << 6;
  const int lane = t & 63, wid = t >> 6;
  const int wm = (wid >> 1) * 32, wn = (wid & 1) * 32;
  const int lr = lane & 15, hi = lane >> 4;
  const int kb = hi * 8, r0 = hi * 4;
  const int xr = lr & 7;

  #pragma unroll
  for (int i = 0; i < 6; ++i)
    GLDS16(wh + (size_t)c0 * 192 + (wid * 6 + i) * 512 + lane * 8,
           &Wsw[(wid * 6 + i) * 512]);

  {
    const _Float16* ysrc = y + (size_t)(tp * 64) * 192;
    uint4 yv[6];
    #pragma unroll
    for (int q = 0; q < 6; ++q) yv[q] = *(const uint4*)(ysrc + (q * 256 + t) * 8);
    #pragma unroll
    for (int q = 0; q < 6; ++q) {
      int id = q * 256 + t;
      *(uint4*)&Bl[(id / 24) * LDK + (id % 24) * 8] = yv[q];
    }
  }
  __syncthreads();

  f32x4 acc[2][2];
  #pragma unroll
  for (int i2 = 0; i2 < 2; ++i2)
    #pragma unroll
    for (int j = 0; j < 2; ++j)
      #pragma unroll
      for (int r = 0; r < 4; ++r) acc[i2][j][r] = 0.0f;

  #pragma unroll
  for (int k6 = 0; k6 < 6; ++k6) {
    const int cs = ((k6 * 4 + hi) ^ xr) << 3;
    half8 a0 = *(const half8*)&Wsw[(wm + lr) * 192 + cs];
    half8 a1 = *(const half8*)&Wsw[(wm + 16 + lr) * 192 + cs];
    half8 b0 = *(const half8*)&Bl[(wn + lr) * LDK + k6 * 32 + kb];
    half8 b1 = *(const half8*)&Bl[(wn + 16 + lr) * LDK + k6 * 32 + kb];
    acc[0][0] = MFMA16(a0, b0, acc[0][0]);
    acc[0][1] = MFMA16(a0, b1, acc[0][1]);
    acc[1][0] = MFMA16(a1, b0, acc[1][0]);
    acc[1][1] = MFMA16(a1, b1, acc[1][1]);
  }

  // D: col = pixel (b-row), row = out-channel (a-row)
  const int gp = tp * 64;
  const int bb = gp >> 12, hw0 = gp & 4095;
  float* op = out + (size_t)bb * 192 * 4096 + hw0;
  #pragma unroll
  for (int i2 = 0; i2 < 2; ++i2)
    #pragma unroll
    for (int j = 0; j < 2; ++j) {
      int m = wn + j * 16 + lr;
      #pragma unroll
      for (int r = 0; r < 4; ++r) {
        int c = c0 + wm + i2 * 16 + r0 + r;
        op[(size_t)c * 4096 + m] = acc[i2][j][r] + bias[c];
      }
    }
}

// ---------------- launch ----------------
extern "C" void kernel_launch(void* const* d_in, const int* in_sizes, int n_in,
                              void* d_out, int out_size, void* d_ws, size_t ws_size,
                              hipStream_t stream) {
  const float* x      = (const float*)d_in[0];
  const float* qkv_w  = (const float*)d_in[1];
  const float* qkv_b  = (const float*)d_in[2];
  const float* proj_w = (const float*)d_in[3];
  const float* proj_b = (const float*)d_in[4];
  const float* rpb0   = (const float*)d_in[5];
  const float* rpb1   = (const float*)d_in[6];
  const float* rpb2   = (const float*)d_in[7];

  // ws layout (~63 MB of ~256 MB): qkv f16, yb f16, xh f16, qwh f16, pwh f16, qbs f32
  _Float16* qkv = (_Float16*)d_ws;                    // 32768*576
  _Float16* yb  = qkv + (size_t)32768 * 576;          // 32768*192
  _Float16* xh  = yb + (size_t)32768 * 192;           // 32768*192
  _Float16* qwh = xh + (size_t)32768 * 192;           // 110592 (swizzled)
  _Float16* pwh = qwh + 110592;                       // 36864  (swizzled)
  float*    qbs = (float*)(pwh + 36864);              // 576
  float* out = (float*)d_out;

  prep<<<dim3(587), 256, 0, stream>>>(x, qkv_w, qkv_b, proj_w, xh, qwh, qbs, pwh);
  qkv_gemm<<<dim3(512), 256, 0, stream>>>(xh, qwh, qbs, qkv);
  natten_all<<<dim3(3344), 256, 0, stream>>>(qkv, rpb0, rpb1, rpb2, yb);
  proj_gemm<<<dim3(512, 3), 256, 0, stream>>>(yb, pwh, proj_b, out);
}

// Round 9
// 135.587 us; speedup vs baseline: 1.3140x; 1.0350x over previous
//
#include <hip/hip_runtime.h>
#include <stdint.h>

// ---------------- common types/helpers ----------------
typedef __attribute__((ext_vector_type(4))) float f32x4;
typedef _Float16 half8 __attribute__((ext_vector_type(8)));
typedef _Float16 half2v __attribute__((ext_vector_type(2)));

#define LDK 200  // padded LDS row pitch (halves): 192+8, rows 400B (16B-aligned)
#define QSCALE 0.17677669529663689f  // 32^-0.5

__device__ __forceinline__ float dot2f(unsigned int k2, unsigned int q2, float c) {
#if __has_builtin(__builtin_amdgcn_fdot2)
  return __builtin_amdgcn_fdot2(__builtin_bit_cast(half2v, k2),
                                __builtin_bit_cast(half2v, q2), c, false);
#else
  half2v a = __builtin_bit_cast(half2v, k2), b = __builtin_bit_cast(half2v, q2);
  return c + (float)a.x * (float)b.x + (float)a.y * (float)b.y;
#endif
}

#define MFMA16(A, B, C) __builtin_amdgcn_mfma_f32_16x16x32_f16(A, B, C, 0, 0, 0)

// async global->LDS, 16B per lane; LDS dest = uniform base + lane*16
#define GLDS16(gsrc, ldst)                                                      \
  __builtin_amdgcn_global_load_lds(                                             \
      (const __attribute__((address_space(1))) void*)(gsrc),                    \
      (__attribute__((address_space(3))) void*)(ldst), 16, 0, 0)

// ---------------- kernel 0: prep (weights only) ----------------
// weights -> f16 in XOR-swizzled chunk layout:
//   W_sw[row*192 + ((chunk ^ (row&7))*8)] = W[row][chunk*8..]  (chunk = 8 halves)
// so a LINEAR global_load_lds image of a 64-row tile is conflict-free under the
// matching ds_read XOR. qkv bias pre-scaled by QSCALE for q-channels.
__global__ __launch_bounds__(256) void prep(
    const float* __restrict__ qw, const float* __restrict__ qb,
    const float* __restrict__ pw,
    _Float16* __restrict__ qwh, float* __restrict__ qbs, _Float16* __restrict__ pwh) {
  int i = blockIdx.x * 256 + threadIdx.x;  // chunk id
  if (i < 13824) {               // qkv_w: 576 rows x 24 chunks
    int n = i / 24, c = i % 24;
    const float* s = qw + n * 192 + c * 8;
    float sc = ((n % 192) < 64) ? QSCALE : 1.0f;
    half8 h = {(_Float16)(s[0] * sc), (_Float16)(s[1] * sc),
               (_Float16)(s[2] * sc), (_Float16)(s[3] * sc),
               (_Float16)(s[4] * sc), (_Float16)(s[5] * sc),
               (_Float16)(s[6] * sc), (_Float16)(s[7] * sc)};
    *(half8*)(qwh + n * 192 + ((c ^ (n & 7)) << 3)) = h;
  } else if (i < 18432) {        // proj_w: 192 rows x 24 chunks
    int k = i - 13824;
    int n = k / 24, c = k % 24;
    const float* s = pw + n * 192 + c * 8;
    half8 h = {(_Float16)s[0], (_Float16)s[1], (_Float16)s[2], (_Float16)s[3],
               (_Float16)s[4], (_Float16)s[5], (_Float16)s[6], (_Float16)s[7]};
    *(half8*)(pwh + n * 192 + ((c ^ (n & 7)) << 3)) = h;
  } else if (i < 19008) {
    int n = i - 18432;
    qbs[n] = qb[n] * (((n % 192) < 64) ? QSCALE : 1.0f);
  }
}

// ---------------- kernel 1: qkv GEMM (x-transpose fused in) ----------------
// Grid 512: one 64-px tile per block. A staged once by transposing x NCHW f32
// directly in LDS (scalar f16 writes, ~4-way conflicts, ~1us total - measured r3).
// 9 W-tiles via DOUBLE-BUFFERED swizzled global_load_lds (zero data VGPRs).
__global__ __launch_bounds__(256) void qkv_gemm(
    const float* __restrict__ x, const _Float16* __restrict__ wh,
    const float* __restrict__ qbs, _Float16* __restrict__ qkv) {
  __shared__ __align__(16) _Float16 Al[64 * LDK];
  __shared__ __align__(16) _Float16 Bsw[2][64 * 192];
  const int t = threadIdx.x;
  const int tm = blockIdx.x;  // 512 pixel tiles
  const int lane = t & 63, wid = t >> 6;
  const int wm = (wid >> 1) * 32, wn = (wid & 1) * 32;
  const int lr = lane & 15, hi = lane >> 4;
  const int kb = hi * 8, r0 = hi * 4;
  const int xr = lr & 7;  // row-XOR for swizzled W reads

  // async: W tile 0 -> LDS (6 instr/wave)
  #pragma unroll
  for (int i = 0; i < 6; ++i)
    GLDS16(wh + (wid * 6 + i) * 512 + lane * 8, &Bsw[0][(wid * 6 + i) * 512]);

  // A tile: transpose x NCHW f32 -> Al[m][c] f16 (fused former prep pass)
  {
    const int bb = tm >> 6, hw0 = (tm & 63) << 6;
    const float* xb = x + (size_t)bb * 192 * 4096 + hw0;
    #pragma unroll
    for (int j = 0; j < 12; ++j) {
      int idx = j * 256 + t;
      int m4 = (idx & 15) * 4, c = idx >> 4;
      float4 v = *(const float4*)(xb + (size_t)c * 4096 + m4);
      Al[(m4 + 0) * LDK + c] = (_Float16)v.x;
      Al[(m4 + 1) * LDK + c] = (_Float16)v.y;
      Al[(m4 + 2) * LDK + c] = (_Float16)v.z;
      Al[(m4 + 3) * LDK + c] = (_Float16)v.w;
    }
  }
  __syncthreads();  // drains A writes + W0 gload_lds (implicit vmcnt(0))

  _Float16* opb = qkv + (size_t)(tm * 64) * 576;
  for (int it = 0; it < 9; ++it) {
    if (it < 8) {  // prefetch next W tile into the other buffer
      const _Float16* wsrc = wh + (it + 1) * 12288;
      _Float16* bdst = &Bsw[(it + 1) & 1][0];
      #pragma unroll
      for (int i = 0; i < 6; ++i)
        GLDS16(wsrc + (wid * 6 + i) * 512 + lane * 8, bdst + (wid * 6 + i) * 512);
    }
    const _Float16* bc = &Bsw[it & 1][0];

    f32x4 acc[2][2];
    #pragma unroll
    for (int i2 = 0; i2 < 2; ++i2)
      #pragma unroll
      for (int j = 0; j < 2; ++j)
        #pragma unroll
        for (int r = 0; r < 4; ++r) acc[i2][j][r] = 0.0f;

    #pragma unroll
    for (int k6 = 0; k6 < 6; ++k6) {
      half8 a0 = *(const half8*)&Al[(wm + lr) * LDK + k6 * 32 + kb];
      half8 a1 = *(const half8*)&Al[(wm + 16 + lr) * LDK + k6 * 32 + kb];
      const int cs = ((k6 * 4 + hi) ^ xr) << 3;  // swizzled chunk offset (halves)
      half8 b0 = *(const half8*)&bc[(wn + lr) * 192 + cs];
      half8 b1 = *(const half8*)&bc[(wn + 16 + lr) * 192 + cs];
      acc[0][0] = MFMA16(a0, b0, acc[0][0]);
      acc[0][1] = MFMA16(a0, b1, acc[0][1]);
      acc[1][0] = MFMA16(a1, b0, acc[1][0]);
      acc[1][1] = MFMA16(a1, b1, acc[1][1]);
    }

    // D: col (= weight n) = lane&15, row (= pixel) = hi*4 + reg
    const int n0 = it * 64;
    const float bs0 = qbs[n0 + wn + lr], bs1 = qbs[n0 + wn + 16 + lr];
    #pragma unroll
    for (int i2 = 0; i2 < 2; ++i2)
      #pragma unroll
      for (int j = 0; j < 2; ++j) {
        int col = n0 + wn + j * 16 + lr;
        float bs = j ? bs1 : bs0;
        #pragma unroll
        for (int r = 0; r < 4; ++r)
          opb[(wm + i2 * 16 + r0 + r) * 576 + col] = (_Float16)(acc[i2][j][r] + bs);
      }
    __syncthreads();  // next W tile arrived; all reads of bc done
  }
}

// ---------------- kernel 2: neighborhood attention (class-tiled, LDS halo) ----------------
template <int K, int DIL>
__device__ __forceinline__ void natten_branch(
    const _Float16* __restrict__ qkv, const float* __restrict__ rpb,
    _Float16* __restrict__ yo, const int branch, const int r,
    unsigned short* __restrict__ smem) {
  constexpr int RW = 2 * K - 1;
  constexpr int H8 = K + 7;        // halo span = 8 + K - 1
  constexpr int NH = H8 * H8;
  constexpr int NL = (K * K + 3) / 4;
  constexpr int LSTR = 40;         // halves per halo row (32 + 8 pad), 80B
  constexpr int NITER = (NH * 8 + 255) / 256;
  constexpr int DH = 32 / H8, DC = 32 % H8;  // px += 32 per staging step

  _Float16* Kl = (_Float16*)smem;
  _Float16* Vl = Kl + NH * LSTR;
  _Float16* Ql = Vl + NH * LSTR;
  float* rs = (float*)(Ql + 64 * LSTR);

  const int t = threadIdx.x;
  const int bh = r & 15;
  const int head = bh & 1, bb = bh >> 1;
  const int rr = r >> 4;
  int gh, gw, ti, tj, Lgh, Lgw;
  if (DIL == 1) {
    gh = 0; gw = 0; ti = (rr >> 3) * 8; tj = (rr & 7) * 8; Lgh = 64; Lgw = 64;
  } else if (DIL == 2) {
    int cls = rr >> 4, tile = rr & 15;
    gh = cls >> 1; gw = cls & 1; ti = (tile >> 2) * 8; tj = (tile & 3) * 8;
    Lgh = 32; Lgw = 32;
  } else {
    int cls = rr / 9, tile = rr % 9;
    gh = cls / 3; gw = cls % 3; ti = (tile / 3) * 8; tj = (tile % 3) * 8;
    Lgh = (64 - gh + 2) / 3; Lgw = (64 - gw + 2) / 3;
  }
  const int hoh = max(0, min(ti - K / 2, Lgh - K));
  const int how = max(0, min(tj - K / 2, Lgw - K));

  for (int i = t; i < RW * RW; i += 256) rs[i] = rpb[head * RW * RW + i];

  // stage halo K/V: part (=t&7) is per-thread constant; px walks +32/iter with
  // incremental row/col (no div/mod in the loop).
  {
    const _Float16* kvb = qkv + (size_t)bb * 4096 * 576 + branch * 192 + 64 + head * 32;
    const int part = t & 7;
    const int coff = (part & 3) * 8;                 // 0,8,16,24 halves
    const _Float16* gsrc = kvb + coff + ((part & 4) ? 64 : 0);
    _Float16* dbase = ((part & 4) ? Vl : Kl) + coff;
    int px = t >> 3;
    int hr = px / H8, hc = px - hr * H8;             // one div at entry
    #pragma unroll
    for (int itn = 0; itn < NITER; ++itn) {
      if (px < NH) {
        int cr = min(hoh + hr, Lgh - 1), cc = min(how + hc, Lgw - 1);
        int ph = gh + cr * DIL, pw2 = gw + cc * DIL;
        *(uint4*)(dbase + px * LSTR) = *(const uint4*)(gsrc + (size_t)(ph * 64 + pw2) * 576);
      }
      px += 32; hr += DH; hc += DC;
      if (hc >= H8) { hc -= H8; ++hr; }
    }
  }
  // stage Q for 64 tile queries (clamped for ragged edges)
  {
    int qi = t >> 2, part = t & 3;
    int ci0 = min(ti + (qi >> 3), Lgh - 1), cj0 = min(tj + (qi & 7), Lgw - 1);
    int ph = gh + ci0 * DIL, pw2 = gw + cj0 * DIL;
    const _Float16* src = qkv + (size_t)((size_t)bb * 4096 + ph * 64 + pw2) * 576
                          + branch * 192 + head * 32 + part * 8;
    *(uint4*)(Ql + qi * LSTR + part * 8) = *(const uint4*)src;
  }
  __syncthreads();

  const int qi = t >> 2, sl = t & 3;
  const int ci = ti + (qi >> 3), cj = tj + (qi & 7);
  const bool valid = (ci < Lgh) && (cj < Lgw);

  int s0h = ci - K / 2; if (s0h < 0) s0h = 0; if (s0h > Lgh - K) s0h = Lgh - K;
  int s0w = cj - K / 2; if (s0w < 0) s0w = 0; if (s0w > Lgw - K) s0w = Lgw - K;
  const int rbase = s0h - hoh, cbase = s0w - how;          // in [0,7]
  const int bhb = s0h - ci + K - 1, bwb = s0w - cj + K - 1;

  // q packed pairs from LDS (broadcast within 4-lane group)
  unsigned int qh[16];
  #pragma unroll
  for (int u = 0; u < 4; ++u) {
    uint4 v = *(const uint4*)(Ql + qi * LSTR + u * 8);
    qh[u * 4 + 0] = v.x; qh[u * 4 + 1] = v.y; qh[u * 4 + 2] = v.z; qh[u * 4 + 3] = v.w;
  }

  // pass 1: scores for this lane's neighbors (n = sl + 4j)
  float s[NL];
  float mx = -1e30f;
  #pragma unroll
  for (int j = 0; j < NL; ++j) {
    int n = sl + 4 * j;
    if (n < K * K) {
      int kh = n / K, kw = n % K;
      int lidx = (rbase + kh) * H8 + (cbase + kw);
      const _Float16* kp = Kl + lidx * LSTR;
      float sc = rs[(bhb + kh) * RW + (bwb + kw)];
      #pragma unroll
      for (int u = 0; u < 4; ++u) {
        uint4 kv = *(const uint4*)(kp + u * 8);
        sc = dot2f(kv.x, qh[4 * u + 0], sc);
        sc = dot2f(kv.y, qh[4 * u + 1], sc);
        sc = dot2f(kv.z, qh[4 * u + 2], sc);
        sc = dot2f(kv.w, qh[4 * u + 3], sc);
      }
      s[j] = sc;
      mx = fmaxf(mx, sc);
    } else {
      s[j] = -1e30f;
    }
  }
  // merge max over the 4 lanes of this query
  mx = fmaxf(mx, __shfl_xor(mx, 1, 64));
  mx = fmaxf(mx, __shfl_xor(mx, 2, 64));

  float pw[NL];
  float l = 0.0f;
  #pragma unroll
  for (int j = 0; j < NL; ++j) { pw[j] = __expf(s[j] - mx); l += pw[j]; }
  l += __shfl_xor(l, 1, 64);
  l += __shfl_xor(l, 2, 64);

  // pass 2: PV with packed f16 accumulation
  half2v acch[16];
  #pragma unroll
  for (int i = 0; i < 16; ++i) acch[i] = (half2v)(_Float16)0.0f;
  #pragma unroll
  for (int j = 0; j < NL; ++j) {
    int n = sl + 4 * j;
    if (n < K * K) {
      int kh = n / K, kw = n % K;
      int lidx = (rbase + kh) * H8 + (cbase + kw);
      const _Float16* vp = Vl + lidx * LSTR;
      _Float16 ph = (_Float16)pw[j];
      half2v pp = {ph, ph};
      #pragma unroll
      for (int u = 0; u < 4; ++u) {
        uint4 vv = *(const uint4*)(vp + u * 8);
        acch[4 * u + 0] += pp * __builtin_bit_cast(half2v, vv.x);
        acch[4 * u + 1] += pp * __builtin_bit_cast(half2v, vv.y);
        acch[4 * u + 2] += pp * __builtin_bit_cast(half2v, vv.z);
        acch[4 * u + 3] += pp * __builtin_bit_cast(half2v, vv.w);
      }
    }
  }
  // butterfly-sum accumulators over the 4 lanes
  #pragma unroll
  for (int st = 1; st <= 2; st <<= 1) {
    #pragma unroll
    for (int i = 0; i < 16; ++i) {
      unsigned int o = __shfl_xor(__builtin_bit_cast(unsigned int, acch[i]), st, 64);
      acch[i] += __builtin_bit_cast(half2v, o);
    }
  }

  if (valid) {
    float inv = 1.0f / l;
    _Float16 ih = (_Float16)inv;
    half2v iv = {ih, ih};
    // lane sl writes dims [8sl, 8sl+8) = pair-regs acch[4sl .. 4sl+3]
    unsigned int a[16];
    #pragma unroll
    for (int i = 0; i < 16; ++i) a[i] = __builtin_bit_cast(unsigned int, acch[i]);
    uint4 pk;
    unsigned int r0, r1, r2, r3;
    r0 = (sl < 2) ? ((sl == 0) ? a[0] : a[4]) : ((sl == 2) ? a[8] : a[12]);
    r1 = (sl < 2) ? ((sl == 0) ? a[1] : a[5]) : ((sl == 2) ? a[9] : a[13]);
    r2 = (sl < 2) ? ((sl == 0) ? a[2] : a[6]) : ((sl == 2) ? a[10] : a[14]);
    r3 = (sl < 2) ? ((sl == 0) ? a[3] : a[7]) : ((sl == 2) ? a[11] : a[15]);
    pk.x = __builtin_bit_cast(unsigned int, __builtin_bit_cast(half2v, r0) * iv);
    pk.y = __builtin_bit_cast(unsigned int, __builtin_bit_cast(half2v, r1) * iv);
    pk.z = __builtin_bit_cast(unsigned int, __builtin_bit_cast(half2v, r2) * iv);
    pk.w = __builtin_bit_cast(unsigned int, __builtin_bit_cast(half2v, r3) * iv);
    const int p = bb * 4096 + (gh + ci * DIL) * 64 + (gw + cj * DIL);
    *(uint4*)(yo + (size_t)p * 192 + branch * 64 + head * 32 + sl * 8) = pk;
  }
}

__global__ __launch_bounds__(256) void natten_all(
    const _Float16* __restrict__ qkv,
    const float* __restrict__ rpb0, const float* __restrict__ rpb1,
    const float* __restrict__ rpb2, _Float16* __restrict__ yo) {
  __shared__ __align__(16) unsigned short smem[18624];  // max: K=7 -> 37.2 KB
  const int gid = blockIdx.x;
  if (gid < 1296)       natten_branch<7, 3>(qkv, rpb2, yo, 2, gid, smem);
  else if (gid < 2320)  natten_branch<5, 2>(qkv, rpb1, yo, 1, gid - 1296, smem);
  else                  natten_branch<3, 1>(qkv, rpb0, yo, 0, gid - 2320, smem);
}

// ---------------- kernel 3: proj GEMM (C^T for coalesced NCHW f32 stores) ----------------
// Grid 512: one 64-px tile per block, y staged ONCE; 3 c-tiles in-loop with
// double-buffered swizzled global_load_lds for W (saves 2x y re-reads vs r8).
__global__ __launch_bounds__(256) void proj_gemm(
    const _Float16* __restrict__ y, const _Float16* __restrict__ wh,
    const float* __restrict__ bias, float* __restrict__ out) {
  __shared__ __align__(16) _Float16 Bl[64 * LDK];      // y (pixels x K), padded
  __shared__ __align__(16) _Float16 Wsw[2][64 * 192];  // W tiles, swizzled-linear
  const int t = threadIdx.x;
  const int tp = blockIdx.x;
  const int lane = t & 63, wid = t >> 6;
  const int wm = (wid >> 1) * 32, wn = (wid & 1) * 32;
  const int lr = lane & 15, hi = lane >> 4;
  const int kb = hi * 8, r0 = hi * 4;
  const int xr = lr & 7;

  // async: W tile 0
  #pragma unroll
  for (int i = 0; i < 6; ++i)
    GLDS16(wh + (wid * 6 + i) * 512 + lane * 8, &Wsw[0][(wid * 6 + i) * 512]);

  // y tile: reg-staged into padded LDS
  {
    const _Float16* ysrc = y + (size_t)(tp * 64) * 192;
    uint4 yv[6];
    #pragma unroll
    for (int q = 0; q < 6; ++q) yv[q] = *(const uint4*)(ysrc + (q * 256 + t) * 8);
    #pragma unroll
    for (int q = 0; q < 6; ++q) {
      int id = q * 256 + t;
      *(uint4*)&Bl[(id / 24) * LDK + (id % 24) * 8] = yv[q];
    }
  }
  __syncthreads();

  const int gp = tp * 64;
  const int bb = gp >> 12, hw0 = gp & 4095;
  float* op = out + (size_t)bb * 192 * 4096 + hw0;

  for (int ci = 0; ci < 3; ++ci) {
    if (ci < 2) {
      const _Float16* wsrc = wh + (ci + 1) * 12288;
      _Float16* wdst = &Wsw[(ci + 1) & 1][0];
      #pragma unroll
      for (int i = 0; i < 6; ++i)
        GLDS16(wsrc + (wid * 6 + i) * 512 + lane * 8, wdst + (wid * 6 + i) * 512);
    }
    const _Float16* wc = &Wsw[ci & 1][0];

    f32x4 acc[2][2];
    #pragma unroll
    for (int i2 = 0; i2 < 2; ++i2)
      #pragma unroll
      for (int j = 0; j < 2; ++j)
        #pragma unroll
        for (int r = 0; r < 4; ++r) acc[i2][j][r] = 0.0f;

    #pragma unroll
    for (int k6 = 0; k6 < 6; ++k6) {
      const int cs = ((k6 * 4 + hi) ^ xr) << 3;
      half8 a0 = *(const half8*)&wc[(wm + lr) * 192 + cs];
      half8 a1 = *(const half8*)&wc[(wm + 16 + lr) * 192 + cs];
      half8 b0 = *(const half8*)&Bl[(wn + lr) * LDK + k6 * 32 + kb];
      half8 b1 = *(const half8*)&Bl[(wn + 16 + lr) * LDK + k6 * 32 + kb];
      acc[0][0] = MFMA16(a0, b0, acc[0][0]);
      acc[0][1] = MFMA16(a0, b1, acc[0][1]);
      acc[1][0] = MFMA16(a1, b0, acc[1][0]);
      acc[1][1] = MFMA16(a1, b1, acc[1][1]);
    }

    // D: col = pixel (b-row), row = out-channel (a-row)
    const int c0 = ci << 6;
    #pragma unroll
    for (int i2 = 0; i2 < 2; ++i2)
      #pragma unroll
      for (int j = 0; j < 2; ++j) {
        int m = wn + j * 16 + lr;
        #pragma unroll
        for (int r = 0; r < 4; ++r) {
          int c = c0 + wm + i2 * 16 + r0 + r;
          op[(size_t)c * 4096 + m] = acc[i2][j][r] + bias[c];
        }
      }
    __syncthreads();
  }
}

// ---------------- launch ----------------
extern "C" void kernel_launch(void* const* d_in, const int* in_sizes, int n_in,
                              void* d_out, int out_size, void* d_ws, size_t ws_size,
                              hipStream_t stream) {
  const float* x      = (const float*)d_in[0];
  const float* qkv_w  = (const float*)d_in[1];
  const float* qkv_b  = (const float*)d_in[2];
  const float* proj_w = (const float*)d_in[3];
  const float* proj_b = (const float*)d_in[4];
  const float* rpb0   = (const float*)d_in[5];
  const float* rpb1   = (const float*)d_in[6];
  const float* rpb2   = (const float*)d_in[7];

  // ws layout (~51 MB of ~256 MB): qkv f16, yb f16, qwh f16, pwh f16, qbs f32
  _Float16* qkv = (_Float16*)d_ws;                    // 32768*576
  _Float16* yb  = qkv + (size_t)32768 * 576;          // 32768*192
  _Float16* qwh = yb + (size_t)32768 * 192;           // 110592 (swizzled)
  _Float16* pwh = qwh + 110592;                       // 36864  (swizzled)
  float*    qbs = (float*)(pwh + 36864);              // 576
  float* out = (float*)d_out;

  prep<<<dim3(75), 256, 0, stream>>>(qkv_w, qkv_b, proj_w, qwh, qbs, pwh);
  qkv_gemm<<<dim3(512), 256, 0, stream>>>(x, qwh, qbs, qkv);
  natten_all<<<dim3(3344), 256, 0, stream>>>(qkv, rpb0, rpb1, rpb2, yb);
  proj_gemm<<<dim3(512), 256, 0, stream>>>(yb, pwh, proj_b, out);
}

// Round 10
// 135.326 us; speedup vs baseline: 1.3165x; 1.0019x over previous
//
#include <hip/hip_runtime.h>
#include <stdint.h>

// ---------------- common types/helpers ----------------
typedef __attribute__((ext_vector_type(4))) float f32x4;
typedef _Float16 half8 __attribute__((ext_vector_type(8)));
typedef _Float16 half2v __attribute__((ext_vector_type(2)));

#define LDK 200  // padded LDS row pitch (halves): 192+8, rows 400B (16B-aligned)
#define LOG2E 1.4426950408889634f
// q-scale with log2(e) folded: scores come out in log2 units -> exp2f (1 instr)
#define QSCALE2 (0.17677669529663689f * 1.4426950408889634f)

__device__ __forceinline__ float dot2f(unsigned int k2, unsigned int q2, float c) {
#if __has_builtin(__builtin_amdgcn_fdot2)
  return __builtin_amdgcn_fdot2(__builtin_bit_cast(half2v, k2),
                                __builtin_bit_cast(half2v, q2), c, false);
#else
  half2v a = __builtin_bit_cast(half2v, k2), b = __builtin_bit_cast(half2v, q2);
  return c + (float)a.x * (float)b.x + (float)a.y * (float)b.y;
#endif
}

#define MFMA16(A, B, C) __builtin_amdgcn_mfma_f32_16x16x32_f16(A, B, C, 0, 0, 0)

// async global->LDS, 16B per lane; LDS dest = uniform base + lane*16
#define GLDS16(gsrc, ldst)                                                      \
  __builtin_amdgcn_global_load_lds(                                             \
      (const __attribute__((address_space(1))) void*)(gsrc),                    \
      (__attribute__((address_space(3))) void*)(ldst), 16, 0, 0)

// ---------------- kernel 0: prep (weights only) ----------------
// weights -> f16 in XOR-swizzled chunk layout (conflict-free under global_load_lds
// + matching ds_read XOR). q-weights/bias carry QSCALE2 (softmax scale * log2e).
__global__ __launch_bounds__(256) void prep(
    const float* __restrict__ qw, const float* __restrict__ qb,
    const float* __restrict__ pw,
    _Float16* __restrict__ qwh, float* __restrict__ qbs, _Float16* __restrict__ pwh) {
  int i = blockIdx.x * 256 + threadIdx.x;  // chunk id
  if (i < 13824) {               // qkv_w: 576 rows x 24 chunks
    int n = i / 24, c = i % 24;
    const float* s = qw + n * 192 + c * 8;
    float sc = ((n % 192) < 64) ? QSCALE2 : 1.0f;
    half8 h = {(_Float16)(s[0] * sc), (_Float16)(s[1] * sc),
               (_Float16)(s[2] * sc), (_Float16)(s[3] * sc),
               (_Float16)(s[4] * sc), (_Float16)(s[5] * sc),
               (_Float16)(s[6] * sc), (_Float16)(s[7] * sc)};
    *(half8*)(qwh + n * 192 + ((c ^ (n & 7)) << 3)) = h;
  } else if (i < 18432) {        // proj_w: 192 rows x 24 chunks
    int k = i - 13824;
    int n = k / 24, c = k % 24;
    const float* s = pw + n * 192 + c * 8;
    half8 h = {(_Float16)s[0], (_Float16)s[1], (_Float16)s[2], (_Float16)s[3],
               (_Float16)s[4], (_Float16)s[5], (_Float16)s[6], (_Float16)s[7]};
    *(half8*)(pwh + n * 192 + ((c ^ (n & 7)) << 3)) = h;
  } else if (i < 19008) {
    int n = i - 18432;
    qbs[n] = qb[n] * (((n % 192) < 64) ? QSCALE2 : 1.0f);
  }
}

// ---------------- kernel 1: qkv GEMM (x-transpose fused in) ----------------
// Grid 512: one 64-px tile per block; A from x NCHW f32 transposed in LDS;
// 9 W-tiles via double-buffered swizzled global_load_lds (zero data VGPRs).
__global__ __launch_bounds__(256) void qkv_gemm(
    const float* __restrict__ x, const _Float16* __restrict__ wh,
    const float* __restrict__ qbs, _Float16* __restrict__ qkv) {
  __shared__ __align__(16) _Float16 Al[64 * LDK];
  __shared__ __align__(16) _Float16 Bsw[2][64 * 192];
  const int t = threadIdx.x;
  const int tm = blockIdx.x;
  const int lane = t & 63, wid = t >> 6;
  const int wm = (wid >> 1) * 32, wn = (wid & 1) * 32;
  const int lr = lane & 15, hi = lane >> 4;
  const int kb = hi * 8, r0 = hi * 4;
  const int xr = lr & 7;

  #pragma unroll
  for (int i = 0; i < 6; ++i)
    GLDS16(wh + (wid * 6 + i) * 512 + lane * 8, &Bsw[0][(wid * 6 + i) * 512]);

  {
    const int bb = tm >> 6, hw0 = (tm & 63) << 6;
    const float* xb = x + (size_t)bb * 192 * 4096 + hw0;
    #pragma unroll
    for (int j = 0; j < 12; ++j) {
      int idx = j * 256 + t;
      int m4 = (idx & 15) * 4, c = idx >> 4;
      float4 v = *(const float4*)(xb + (size_t)c * 4096 + m4);
      Al[(m4 + 0) * LDK + c] = (_Float16)v.x;
      Al[(m4 + 1) * LDK + c] = (_Float16)v.y;
      Al[(m4 + 2) * LDK + c] = (_Float16)v.z;
      Al[(m4 + 3) * LDK + c] = (_Float16)v.w;
    }
  }
  __syncthreads();

  _Float16* opb = qkv + (size_t)(tm * 64) * 576;
  for (int it = 0; it < 9; ++it) {
    if (it < 8) {
      const _Float16* wsrc = wh + (it + 1) * 12288;
      _Float16* bdst = &Bsw[(it + 1) & 1][0];
      #pragma unroll
      for (int i = 0; i < 6; ++i)
        GLDS16(wsrc + (wid * 6 + i) * 512 + lane * 8, bdst + (wid * 6 + i) * 512);
    }
    const _Float16* bc = &Bsw[it & 1][0];

    f32x4 acc[2][2];
    #pragma unroll
    for (int i2 = 0; i2 < 2; ++i2)
      #pragma unroll
      for (int j = 0; j < 2; ++j)
        #pragma unroll
        for (int r = 0; r < 4; ++r) acc[i2][j][r] = 0.0f;

    #pragma unroll
    for (int k6 = 0; k6 < 6; ++k6) {
      half8 a0 = *(const half8*)&Al[(wm + lr) * LDK + k6 * 32 + kb];
      half8 a1 = *(const half8*)&Al[(wm + 16 + lr) * LDK + k6 * 32 + kb];
      const int cs = ((k6 * 4 + hi) ^ xr) << 3;
      half8 b0 = *(const half8*)&bc[(wn + lr) * 192 + cs];
      half8 b1 = *(const half8*)&bc[(wn + 16 + lr) * 192 + cs];
      acc[0][0] = MFMA16(a0, b0, acc[0][0]);
      acc[0][1] = MFMA16(a0, b1, acc[0][1]);
      acc[1][0] = MFMA16(a1, b0, acc[1][0]);
      acc[1][1] = MFMA16(a1, b1, acc[1][1]);
    }

    const int n0 = it * 64;
    const float bs0 = qbs[n0 + wn + lr], bs1 = qbs[n0 + wn + 16 + lr];
    #pragma unroll
    for (int i2 = 0; i2 < 2; ++i2)
      #pragma unroll
      for (int j = 0; j < 2; ++j) {
        int col = n0 + wn + j * 16 + lr;
        float bs = j ? bs1 : bs0;
        #pragma unroll
        for (int r = 0; r < 4; ++r)
          opb[(wm + i2 * 16 + r0 + r) * 576 + col] = (_Float16)(acc[i2][j][r] + bs);
      }
    __syncthreads();
  }
}

// ---------------- kernel 2: neighborhood attention (class-tiled, LDS halo) ----------------
// r10: merged K|V rows (LSTR=72 -> 28.9KB LDS, 5 blocks/CU), Q direct from global,
// in-place exp over s[] (register diet vs r9's s+pw), exp2f throughout.
template <int K, int DIL>
__device__ __forceinline__ void natten_branch(
    const _Float16* __restrict__ qkv, const float* __restrict__ rpb,
    _Float16* __restrict__ yo, const int branch, const int r,
    unsigned short* __restrict__ smem) {
  constexpr int RW = 2 * K - 1;
  constexpr int H8 = K + 7;
  constexpr int NH = H8 * H8;
  constexpr int NL = (K * K + 3) / 4;
  constexpr int LSTR = 72;  // halves: 32 K | 32 V | 8 pad (144B rows, b128-aligned)
  constexpr int NITER = (NH * 8 + 255) / 256;
  constexpr int DH = 32 / H8, DC = 32 % H8;

  _Float16* KV = (_Float16*)smem;
  float* rs = (float*)(KV + NH * LSTR);

  const int t = threadIdx.x;
  const int bh = r & 15;
  const int head = bh & 1, bb = bh >> 1;
  const int rr = r >> 4;
  int gh, gw, ti, tj, Lgh, Lgw;
  if (DIL == 1) {
    gh = 0; gw = 0; ti = (rr >> 3) * 8; tj = (rr & 7) * 8; Lgh = 64; Lgw = 64;
  } else if (DIL == 2) {
    int cls = rr >> 4, tile = rr & 15;
    gh = cls >> 1; gw = cls & 1; ti = (tile >> 2) * 8; tj = (tile & 3) * 8;
    Lgh = 32; Lgw = 32;
  } else {
    int cls = rr / 9, tile = rr % 9;
    gh = cls / 3; gw = cls % 3; ti = (tile / 3) * 8; tj = (tile % 3) * 8;
    Lgh = (64 - gh + 2) / 3; Lgw = (64 - gw + 2) / 3;
  }
  const int hoh = max(0, min(ti - K / 2, Lgh - K));
  const int how = max(0, min(tj - K / 2, Lgw - K));

  for (int i = t; i < RW * RW; i += 256) rs[i] = rpb[head * RW * RW + i] * LOG2E;

  // stage halo K|V merged rows; incremental px addressing (r9 pattern)
  {
    const _Float16* kvb = qkv + (size_t)bb * 4096 * 576 + branch * 192 + 64 + head * 32;
    const int part = t & 7;
    const _Float16* gsrc = kvb + (part & 3) * 8 + ((part & 4) ? 64 : 0);
    _Float16* dbase = KV + part * 8;  // linear within merged row
    int px = t >> 3;
    int hr = px / H8, hc = px - hr * H8;
    #pragma unroll
    for (int itn = 0; itn < NITER; ++itn) {
      if (px < NH) {
        int cr = min(hoh + hr, Lgh - 1), cc = min(how + hc, Lgw - 1);
        int ph = gh + cr * DIL, pw2 = gw + cc * DIL;
        *(uint4*)(dbase + px * LSTR) = *(const uint4*)(gsrc + (size_t)(ph * 64 + pw2) * 576);
      }
      px += 32; hr += DH; hc += DC;
      if (hc >= H8) { hc -= H8; ++hr; }
    }
  }

  const int qi = t >> 2, sl = t & 3;
  const int ci = ti + (qi >> 3), cj = tj + (qi & 7);
  const bool valid = (ci < Lgh) && (cj < Lgw);
  const int cic = min(ci, Lgh - 1), cjc = min(cj, Lgw - 1);
  const int p = bb * 4096 + (gh + cic * DIL) * 64 + (gw + cjc * DIL);

  // Q direct from global (L2-warm; 4 lanes/query share the 64B line)
  unsigned int qh[16];
  {
    const _Float16* qp = qkv + (size_t)p * 576 + branch * 192 + head * 32;
    #pragma unroll
    for (int u = 0; u < 4; ++u) {
      uint4 v = *(const uint4*)(qp + u * 8);
      qh[u * 4 + 0] = v.x; qh[u * 4 + 1] = v.y; qh[u * 4 + 2] = v.z; qh[u * 4 + 3] = v.w;
    }
  }

  int s0h = ci - K / 2; if (s0h < 0) s0h = 0; if (s0h > Lgh - K) s0h = Lgh - K;
  int s0w = cj - K / 2; if (s0w < 0) s0w = 0; if (s0w > Lgw - K) s0w = Lgw - K;
  const int rbase = s0h - hoh, cbase = s0w - how;
  const int bhb = s0h - ci + K - 1, bwb = s0w - cj + K - 1;

  __syncthreads();

  // pass 1: scores for this lane's neighbors (n = sl + 4j); exp2 in place
  float s[NL];
  float mx = -1e30f;
  #pragma unroll
  for (int j = 0; j < NL; ++j) {
    int n = sl + 4 * j;
    if (n < K * K) {
      int kh = n / K, kw = n % K;
      int lidx = (rbase + kh) * H8 + (cbase + kw);
      const _Float16* kp = KV + lidx * LSTR;
      float sc = rs[(bhb + kh) * RW + (bwb + kw)];
      #pragma unroll
      for (int u = 0; u < 4; ++u) {
        uint4 kv = *(const uint4*)(kp + u * 8);
        sc = dot2f(kv.x, qh[4 * u + 0], sc);
        sc = dot2f(kv.y, qh[4 * u + 1], sc);
        sc = dot2f(kv.z, qh[4 * u + 2], sc);
        sc = dot2f(kv.w, qh[4 * u + 3], sc);
      }
      s[j] = sc;
      mx = fmaxf(mx, sc);
    } else {
      s[j] = -1e30f;
    }
  }
  mx = fmaxf(mx, __shfl_xor(mx, 1, 64));
  mx = fmaxf(mx, __shfl_xor(mx, 2, 64));

  float l = 0.0f;
  #pragma unroll
  for (int j = 0; j < NL; ++j) { float pv = exp2f(s[j] - mx); s[j] = pv; l += pv; }
  l += __shfl_xor(l, 1, 64);
  l += __shfl_xor(l, 2, 64);

  // pass 2: PV with packed f16 accumulation (V at +32 in merged row)
  half2v acch[16];
  #pragma unroll
  for (int i = 0; i < 16; ++i) acch[i] = (half2v)(_Float16)0.0f;
  #pragma unroll
  for (int j = 0; j < NL; ++j) {
    int n = sl + 4 * j;
    if (n < K * K) {
      int kh = n / K, kw = n % K;
      int lidx = (rbase + kh) * H8 + (cbase + kw);
      const _Float16* vp = KV + lidx * LSTR + 32;
      _Float16 ph = (_Float16)s[j];
      half2v pp = {ph, ph};
      #pragma unroll
      for (int u = 0; u < 4; ++u) {
        uint4 vv = *(const uint4*)(vp + u * 8);
        acch[4 * u + 0] += pp * __builtin_bit_cast(half2v, vv.x);
        acch[4 * u + 1] += pp * __builtin_bit_cast(half2v, vv.y);
        acch[4 * u + 2] += pp * __builtin_bit_cast(half2v, vv.z);
        acch[4 * u + 3] += pp * __builtin_bit_cast(half2v, vv.w);
      }
    }
  }
  // butterfly-sum accumulators over the 4 lanes
  #pragma unroll
  for (int st = 1; st <= 2; st <<= 1) {
    #pragma unroll
    for (int i = 0; i < 16; ++i) {
      unsigned int o = __shfl_xor(__builtin_bit_cast(unsigned int, acch[i]), st, 64);
      acch[i] += __builtin_bit_cast(half2v, o);
    }
  }

  if (valid) {
    float inv = 1.0f / l;
    _Float16 ih = (_Float16)inv;
    half2v iv = {ih, ih};
    unsigned int a[16];
    #pragma unroll
    for (int i = 0; i < 16; ++i) a[i] = __builtin_bit_cast(unsigned int, acch[i]);
    uint4 pk;
    unsigned int r0, r1, r2, r3;
    r0 = (sl < 2) ? ((sl == 0) ? a[0] : a[4]) : ((sl == 2) ? a[8] : a[12]);
    r1 = (sl < 2) ? ((sl == 0) ? a[1] : a[5]) : ((sl == 2) ? a[9] : a[13]);
    r2 = (sl < 2) ? ((sl == 0) ? a[2] : a[6]) : ((sl == 2) ? a[10] : a[14]);
    r3 = (sl < 2) ? ((sl == 0) ? a[3] : a[7]) : ((sl == 2) ? a[11] : a[15]);
    pk.x = __builtin_bit_cast(unsigned int, __builtin_bit_cast(half2v, r0) * iv);
    pk.y = __builtin_bit_cast(unsigned int, __builtin_bit_cast(half2v, r1) * iv);
    pk.z = __builtin_bit_cast(unsigned int, __builtin_bit_cast(half2v, r2) * iv);
    pk.w = __builtin_bit_cast(unsigned int, __builtin_bit_cast(half2v, r3) * iv);
    *(uint4*)(yo + (size_t)p * 192 + branch * 64 + head * 32 + sl * 8) = pk;
  }
}

__global__ __launch_bounds__(256) void natten_all(
    const _Float16* __restrict__ qkv,
    const float* __restrict__ rpb0, const float* __restrict__ rpb1,
    const float* __restrict__ rpb2, _Float16* __restrict__ yo) {
  __shared__ __align__(16) unsigned short smem[14464];  // K=7: 196*72*2 + 169*4 = 28.9KB
  const int gid = blockIdx.x;
  if (gid < 1296)       natten_branch<7, 3>(qkv, rpb2, yo, 2, gid, smem);
  else if (gid < 2320)  natten_branch<5, 2>(qkv, rpb1, yo, 1, gid - 1296, smem);
  else                  natten_branch<3, 1>(qkv, rpb0, yo, 0, gid - 2320, smem);
}

// ---------------- kernel 3: proj GEMM (C^T for coalesced NCHW f32 stores) ----------------
__global__ __launch_bounds__(256) void proj_gemm(
    const _Float16* __restrict__ y, const _Float16* __restrict__ wh,
    const float* __restrict__ bias, float* __restrict__ out) {
  __shared__ __align__(16) _Float16 Bl[64 * LDK];
  __shared__ __align__(16) _Float16 Wsw[2][64 * 192];
  const int t = threadIdx.x;
  const int tp = blockIdx.x;
  const int lane = t & 63, wid = t >> 6;
  const int wm = (wid >> 1) * 32, wn = (wid & 1) * 32;
  const int lr = lane & 15, hi = lane >> 4;
  const int kb = hi * 8, r0 = hi * 4;
  const int xr = lr & 7;

  #pragma unroll
  for (int i = 0; i < 6; ++i)
    GLDS16(wh + (wid * 6 + i) * 512 + lane * 8, &Wsw[0][(wid * 6 + i) * 512]);

  {
    const _Float16* ysrc = y + (size_t)(tp * 64) * 192;
    uint4 yv[6];
    #pragma unroll
    for (int q = 0; q < 6; ++q) yv[q] = *(const uint4*)(ysrc + (q * 256 + t) * 8);
    #pragma unroll
    for (int q = 0; q < 6; ++q) {
      int id = q * 256 + t;
      *(uint4*)&Bl[(id / 24) * LDK + (id % 24) * 8] = yv[q];
    }
  }
  __syncthreads();

  const int gp = tp * 64;
  const int bb = gp >> 12, hw0 = gp & 4095;
  float* op = out + (size_t)bb * 192 * 4096 + hw0;

  for (int ci = 0; ci < 3; ++ci) {
    if (ci < 2) {
      const _Float16* wsrc = wh + (ci + 1) * 12288;
      _Float16* wdst = &Wsw[(ci + 1) & 1][0];
      #pragma unroll
      for (int i = 0; i < 6; ++i)
        GLDS16(wsrc + (wid * 6 + i) * 512 + lane * 8, wdst + (wid * 6 + i) * 512);
    }
    const _Float16* wc = &Wsw[ci & 1][0];

    f32x4 acc[2][2];
    #pragma unroll
    for (int i2 = 0; i2 < 2; ++i2)
      #pragma unroll
      for (int j = 0; j < 2; ++j)
        #pragma unroll
        for (int r = 0; r < 4; ++r) acc[i2][j][r] = 0.0f;

    #pragma unroll
    for (int k6 = 0; k6 < 6; ++k6) {
      const int cs = ((k6 * 4 + hi) ^ xr) << 3;
      half8 a0 = *(const half8*)&wc[(wm + lr) * 192 + cs];
      half8 a1 = *(const half8*)&wc[(wm + 16 + lr) * 192 + cs];
      half8 b0 = *(const half8*)&Bl[(wn + lr) * LDK + k6 * 32 + kb];
      half8 b1 = *(const half8*)&Bl[(wn + 16 + lr) * LDK + k6 * 32 + kb];
      acc[0][0] = MFMA16(a0, b0, acc[0][0]);
      acc[0][1] = MFMA16(a0, b1, acc[0][1]);
      acc[1][0] = MFMA16(a1, b0, acc[1][0]);
      acc[1][1] = MFMA16(a1, b1, acc[1][1]);
    }

    const int c0 = ci << 6;
    #pragma unroll
    for (int i2 = 0; i2 < 2; ++i2)
      #pragma unroll
      for (int j = 0; j < 2; ++j) {
        int m = wn + j * 16 + lr;
        #pragma unroll
        for (int r = 0; r < 4; ++r) {
          int c = c0 + wm + i2 * 16 + r0 + r;
          op[(size_t)c * 4096 + m] = acc[i2][j][r] + bias[c];
        }
      }
    __syncthreads();
  }
}

// ---------------- launch ----------------
extern "C" void kernel_launch(void* const* d_in, const int* in_sizes, int n_in,
                              void* d_out, int out_size, void* d_ws, size_t ws_size,
                              hipStream_t stream) {
  const float* x      = (const float*)d_in[0];
  const float* qkv_w  = (const float*)d_in[1];
  const float* qkv_b  = (const float*)d_in[2];
  const float* proj_w = (const float*)d_in[3];
  const float* proj_b = (const float*)d_in[4];
  const float* rpb0   = (const float*)d_in[5];
  const float* rpb1   = (const float*)d_in[6];
  const float* rpb2   = (const float*)d_in[7];

  _Float16* qkv = (_Float16*)d_ws;                    // 32768*576
  _Float16* yb  = qkv + (size_t)32768 * 576;          // 32768*192
  _Float16* qwh = yb + (size_t)32768 * 192;           // 110592 (swizzled)
  _Float16* pwh = qwh + 110592;                       // 36864  (swizzled)
  float*    qbs = (float*)(pwh + 36864);              // 576
  float* out = (float*)d_out;

  prep<<<dim3(75), 256, 0, stream>>>(qkv_w, qkv_b, proj_w, qwh, qbs, pwh);
  qkv_gemm<<<dim3(512), 256, 0, stream>>>(x, qwh, qbs, qkv);
  natten_all<<<dim3(3344), 256, 0, stream>>>(qkv, rpb0, rpb1, rpb2, yb);
  proj_gemm<<<dim3(512), 256, 0, stream>>>(yb, pwh, proj_b, out);
}